// Round 2
// baseline (478.308 us; speedup 1.0000x reference)
//
#include <hip/hip_runtime.h>
#include <hip/hip_bf16.h>

// Problem constants (reference: B=1, H=8, L=4096, D=64, 64x64 blocks, 16 samples)
// Inputs q,k,v are FLOAT32 (reference setup_inputs uses jnp.float32); output f32.
#define H_ 8
#define L_ 4096
#define D_ 64
#define NB_ 64   // L_/64 blocks per dimension

// ---------------------------------------------------------------------------
// Kernel A: block mask. One block per (h, qb). 256 threads.
// Pooled downsampled attention over 16 sampled q rows vs 1024 sampled k rows;
// attend(kb) = mass_before(kb)/total < 0.5 with stable descending-rank
// tie-break (equal values: lower index ranks first), matching jnp.argsort.
// Writes one 64-bit mask word per (h,qb) into workspace.
// ---------------------------------------------------------------------------
__global__ __launch_bounds__(256) void mask_kernel(
    const float* __restrict__ q,
    const float* __restrict__ k,
    const int* __restrict__ sidxq,
    const int* __restrict__ sidxk,
    unsigned long long* __restrict__ maskbits)
{
    const int h   = blockIdx.x >> 6;
    const int qb  = blockIdx.x & 63;
    const int tid = threadIdx.x;

    __shared__ float sq[16][68];     // sampled q rows
    __shared__ float sc[8][1024];    // half of the score matrix (32 KB)
    __shared__ float rowm[8], rowz[8];
    __shared__ float red[8][17];
    __shared__ float pooled[64];
    __shared__ int   iq[16], ik[16];

    if (tid < 16) { iq[tid] = sidxq[h*16 + tid]; ik[tid] = sidxk[h*16 + tid]; }
    if (tid < 64) pooled[tid] = 0.f;
    __syncthreads();

    for (int e = tid; e < 16*64; e += 256) {
        int j = e >> 6, d = e & 63;
        sq[j][d] = q[((size_t)h*L_ + (size_t)qb*64 + iq[j])*D_ + d];
    }
    __syncthreads();

    for (int half = 0; half < 2; ++half) {
        const int jb = half * 8;   // q rows jb..jb+7, full 1024-column softmax rows
        for (int kk = tid; kk < 1024; kk += 256) {
            int kb2 = kk >> 4, tt = kk & 15;
            const float* kp = k + ((size_t)h*L_ + (size_t)kb2*64 + ik[tt])*D_;
            float kr[64];
            #pragma unroll
            for (int c4 = 0; c4 < 16; ++c4) {
                float4 u = *(const float4*)(kp + c4*4);
                kr[c4*4+0] = u.x; kr[c4*4+1] = u.y;
                kr[c4*4+2] = u.z; kr[c4*4+3] = u.w;
            }
            #pragma unroll
            for (int j = 0; j < 8; ++j) {
                float acc = 0.f;
                #pragma unroll
                for (int d4 = 0; d4 < 16; ++d4) {
                    float4 qv = *(const float4*)&sq[jb + j][d4*4];
                    acc += qv.x * kr[d4*4+0];
                    acc += qv.y * kr[d4*4+1];
                    acc += qv.z * kr[d4*4+2];
                    acc += qv.w * kr[d4*4+3];
                }
                sc[j][kk] = acc * 0.125f;   // 1/sqrt(64)
            }
        }
        __syncthreads();
        // row max
        if (tid < 128) {
            int j = tid >> 4, g = tid & 15;
            float mm = -1e30f;
            for (int x = 0; x < 64; ++x) mm = fmaxf(mm, sc[j][g*64 + x]);
            red[j][g] = mm;
        }
        __syncthreads();
        if (tid < 8) {
            float mm = -1e30f;
            for (int g = 0; g < 16; ++g) mm = fmaxf(mm, red[tid][g]);
            rowm[tid] = mm;
        }
        __syncthreads();
        // exp in place + partial sums
        if (tid < 128) {
            int j = tid >> 4, g = tid & 15;
            float m2 = rowm[j], z = 0.f;
            for (int x = 0; x < 64; ++x) {
                float e2 = expf(sc[j][g*64 + x] - m2);
                sc[j][g*64 + x] = e2;
                z += e2;
            }
            red[j][g] = z;
        }
        __syncthreads();
        if (tid < 8) {
            float z = 0.f;
            for (int g = 0; g < 16; ++g) z += red[tid][g];
            rowz[tid] = z;
        }
        __syncthreads();
        // pooled mass per key block
        if (tid < 64) {
            float acc = pooled[tid];
            for (int j = 0; j < 8; ++j) {
                float ss = 0.f;
                for (int tt = 0; tt < 16; ++tt) ss += sc[j][tid*16 + tt];
                acc += ss / rowz[j];
            }
            pooled[tid] = acc;
        }
        __syncthreads();
    }

    // top-p 0.5 selection without sorting
    if (tid < 64) {
        float pi = pooled[tid];
        float tot = 0.f, bef = 0.f;
        for (int j2 = 0; j2 < 64; ++j2) {
            float pj = pooled[j2];
            tot += pj;
            if (pj > pi || (pj == pi && j2 < tid)) bef += pj;
        }
        bool att = (bef / tot) < 0.5f;
        unsigned long long bits = __ballot(att);   // wave 0, 64-bit
        if (tid == 0) maskbits[(h << 6) + qb] = bits;
    }
}

// ---------------------------------------------------------------------------
// Kernel B: block-sparse flash attention. One block per (h, qb). 256 threads.
// Thread t owns O[r0..r0+3][c0..c0+3], r0=(t>>4)*4, c0=(t&15)*4.
// kpbuf holds K^T during S=QK^T, then is reused for P (K^T is dead after S).
// LDS: 3 x 64x68 f32 = 51 KB.
// ---------------------------------------------------------------------------
__global__ __launch_bounds__(256) void attn_kernel(
    const float* __restrict__ q,
    const float* __restrict__ k,
    const float* __restrict__ v,
    const unsigned long long* __restrict__ maskbits,
    float* __restrict__ out)
{
    const int h   = blockIdx.x >> 6;
    const int qb  = blockIdx.x & 63;
    const int tid = threadIdx.x;
    const int r0  = (tid >> 4) << 2;
    const int c0  = (tid & 15) << 2;

    __shared__ float qs[64][68];       // Q tile, row-major
    __shared__ float kpbuf[64][68];    // K^T (ksT[d][c]) then P (st[r][kk])
    __shared__ float vs[64][68];       // V row-major

    const float4* qb4 = (const float4*)(q + ((size_t)h*L_ + (size_t)qb*64)*D_);
    for (int i4 = tid; i4 < 1024; i4 += 256) {
        float4 t4 = qb4[i4];
        *(float4*)&qs[i4 >> 4][(i4 & 15) << 2] = t4;
    }

    const unsigned long long bm = maskbits[(h << 6) + qb];

    float m_i[4], l_i[4], o_acc[4][4];
    #pragma unroll
    for (int i = 0; i < 4; ++i) {
        m_i[i] = -1e30f; l_i[i] = 0.f;
        #pragma unroll
        for (int j = 0; j < 4; ++j) o_acc[i][j] = 0.f;
    }
    __syncthreads();

    for (int kb = 0; kb < 64; ++kb) {
        if (!((bm >> kb) & 1ull)) continue;   // block-uniform branch

        // stage K^T (transposed scatter) and V (row-major)
        const float4* kb4 = (const float4*)(k + ((size_t)h*L_ + (size_t)kb*64)*D_);
        const float4* vb4 = (const float4*)(v + ((size_t)h*L_ + (size_t)kb*64)*D_);
        for (int i4 = tid; i4 < 1024; i4 += 256) {
            int r = i4 >> 4, c = (i4 & 15) << 2;
            float4 t4 = kb4[i4];
            kpbuf[c + 0][r] = t4.x; kpbuf[c + 1][r] = t4.y;
            kpbuf[c + 2][r] = t4.z; kpbuf[c + 3][r] = t4.w;
            float4 u4 = vb4[i4];
            *(float4*)&vs[r][c] = u4;
        }
        __syncthreads();

        // S = Q K^T * 0.125 (4x4 register tile); rows uniform per read -> no conflicts
        float s[4][4] = {{0.f,0.f,0.f,0.f},{0.f,0.f,0.f,0.f},
                         {0.f,0.f,0.f,0.f},{0.f,0.f,0.f,0.f}};
        #pragma unroll
        for (int d4 = 0; d4 < 16; ++d4) {
            float qv[4][4];
            #pragma unroll
            for (int i = 0; i < 4; ++i)
                *(float4*)&qv[i][0] = *(const float4*)&qs[r0 + i][d4 << 2];
            #pragma unroll
            for (int dd = 0; dd < 4; ++dd) {
                float4 kv = *(const float4*)&kpbuf[(d4 << 2) + dd][c0];
                #pragma unroll
                for (int i = 0; i < 4; ++i) {
                    s[i][0] += qv[i][dd] * kv.x;
                    s[i][1] += qv[i][dd] * kv.y;
                    s[i][2] += qv[i][dd] * kv.z;
                    s[i][3] += qv[i][dd] * kv.w;
                }
            }
        }
        #pragma unroll
        for (int i = 0; i < 4; ++i)
            #pragma unroll
            for (int j = 0; j < 4; ++j) s[i][j] *= 0.125f;

        // row max across the 16-lane group sharing r0
        float rowmax[4];
        #pragma unroll
        for (int i = 0; i < 4; ++i)
            rowmax[i] = fmaxf(fmaxf(s[i][0], s[i][1]), fmaxf(s[i][2], s[i][3]));
        #pragma unroll
        for (int off = 1; off < 16; off <<= 1)
            #pragma unroll
            for (int i = 0; i < 4; ++i)
                rowmax[i] = fmaxf(rowmax[i], __shfl_xor(rowmax[i], off));

        __syncthreads();   // all K^T reads done before kpbuf is overwritten as P

        float al[4], rs[4];
        #pragma unroll
        for (int i = 0; i < 4; ++i) {
            float mnew = fmaxf(m_i[i], rowmax[i]);
            al[i] = expf(m_i[i] - mnew);
            m_i[i] = mnew;
            float p0 = expf(s[i][0] - mnew);
            float p1 = expf(s[i][1] - mnew);
            float p2 = expf(s[i][2] - mnew);
            float p3 = expf(s[i][3] - mnew);
            kpbuf[r0 + i][c0 + 0] = p0; kpbuf[r0 + i][c0 + 1] = p1;
            kpbuf[r0 + i][c0 + 2] = p2; kpbuf[r0 + i][c0 + 3] = p3;
            rs[i] = (p0 + p1) + (p2 + p3);
        }
        #pragma unroll
        for (int off = 1; off < 16; off <<= 1)
            #pragma unroll
            for (int i = 0; i < 4; ++i)
                rs[i] += __shfl_xor(rs[i], off);
        #pragma unroll
        for (int i = 0; i < 4; ++i) {
            l_i[i] = l_i[i] * al[i] + rs[i];
            #pragma unroll
            for (int j = 0; j < 4; ++j) o_acc[i][j] *= al[i];
        }
        __syncthreads();   // P fully written before PV reads

        // O += P V
        #pragma unroll
        for (int kk = 0; kk < 64; kk += 4) {
            float p4[4][4];
            #pragma unroll
            for (int i = 0; i < 4; ++i)
                *(float4*)&p4[i][0] = *(const float4*)&kpbuf[r0 + i][kk];
            #pragma unroll
            for (int dd = 0; dd < 4; ++dd) {
                float4 v4 = *(const float4*)&vs[kk + dd][c0];
                #pragma unroll
                for (int i = 0; i < 4; ++i) {
                    float pw = p4[i][dd];
                    o_acc[i][0] += pw * v4.x;
                    o_acc[i][1] += pw * v4.y;
                    o_acc[i][2] += pw * v4.z;
                    o_acc[i][3] += pw * v4.w;
                }
            }
        }
        __syncthreads();   // P/V reads done before next iteration's staging
    }

    // epilogue: O / l
    float* obase = out + ((size_t)h*L_ + (size_t)qb*64)*D_;
    #pragma unroll
    for (int i = 0; i < 4; ++i) {
        float inv = 1.f / l_i[i];
        float4 o4;
        o4.x = o_acc[i][0] * inv; o4.y = o_acc[i][1] * inv;
        o4.z = o_acc[i][2] * inv; o4.w = o_acc[i][3] * inv;
        *(float4*)&obase[(size_t)(r0 + i)*D_ + c0] = o4;
    }
}

extern "C" void kernel_launch(void* const* d_in, const int* in_sizes, int n_in,
                              void* d_out, int out_size, void* d_ws, size_t ws_size,
                              hipStream_t stream) {
    const float* q = (const float*)d_in[0];
    const float* k = (const float*)d_in[1];
    const float* v = (const float*)d_in[2];
    const int* siq = (const int*)d_in[3];
    const int* sik = (const int*)d_in[4];
    float* out = (float*)d_out;
    unsigned long long* mask = (unsigned long long*)d_ws;  // 512 x 8B = 4 KB

    mask_kernel<<<dim3(H_*NB_), dim3(256), 0, stream>>>(q, k, siq, sik, mask);
    attn_kernel<<<dim3(H_*NB_), dim3(256), 0, stream>>>(q, k, v, mask, out);
}

// Round 3
// 302.781 us; speedup vs baseline: 1.5797x; 1.5797x over previous
//
#include <hip/hip_runtime.h>
#include <hip/hip_bf16.h>

// Problem constants (reference: B=1, H=8, L=4096, D=64, 64x64 blocks, 16 samples)
// Inputs q,k,v are FLOAT32; output f32.
#define H_ 8
#define L_ 4096
#define D_ 64
#define NB_ 64   // L_/64 blocks per dimension
#define PADB 72  // bf16 LDS row pad: 144 B stride keeps 16B alignment for b128

typedef __attribute__((ext_vector_type(8))) short bf16x8;
typedef __attribute__((ext_vector_type(4))) float f32x4;

__device__ __forceinline__ unsigned short f2bf(float x) {   // RNE f32->bf16
    unsigned u = __float_as_uint(x);
    u += 0x7fff + ((u >> 16) & 1);
    return (unsigned short)(u >> 16);
}
__device__ __forceinline__ float bf2f(unsigned short s) {
    return __uint_as_float(((unsigned)s) << 16);
}

// ---------------------------------------------------------------------------
// Kernel A: block mask — UNCHANGED from the passing round-2 version.
// Mask decision must remain f32: bf16 scores shift pooled mass ~1e-3 rel,
// enough to flip blocks at the cumulative-0.5 boundary (2% mass each).
// ---------------------------------------------------------------------------
__global__ __launch_bounds__(256) void mask_kernel(
    const float* __restrict__ q,
    const float* __restrict__ k,
    const int* __restrict__ sidxq,
    const int* __restrict__ sidxk,
    unsigned long long* __restrict__ maskbits)
{
    const int h   = blockIdx.x >> 6;
    const int qb  = blockIdx.x & 63;
    const int tid = threadIdx.x;

    __shared__ float sq[16][68];
    __shared__ float sc[8][1024];
    __shared__ float rowm[8], rowz[8];
    __shared__ float red[8][17];
    __shared__ float pooled[64];
    __shared__ int   iq[16], ik[16];

    if (tid < 16) { iq[tid] = sidxq[h*16 + tid]; ik[tid] = sidxk[h*16 + tid]; }
    if (tid < 64) pooled[tid] = 0.f;
    __syncthreads();

    for (int e = tid; e < 16*64; e += 256) {
        int j = e >> 6, d = e & 63;
        sq[j][d] = q[((size_t)h*L_ + (size_t)qb*64 + iq[j])*D_ + d];
    }
    __syncthreads();

    for (int half = 0; half < 2; ++half) {
        const int jb = half * 8;
        for (int kk = tid; kk < 1024; kk += 256) {
            int kb2 = kk >> 4, tt = kk & 15;
            const float* kp = k + ((size_t)h*L_ + (size_t)kb2*64 + ik[tt])*D_;
            float kr[64];
            #pragma unroll
            for (int c4 = 0; c4 < 16; ++c4) {
                float4 u = *(const float4*)(kp + c4*4);
                kr[c4*4+0] = u.x; kr[c4*4+1] = u.y;
                kr[c4*4+2] = u.z; kr[c4*4+3] = u.w;
            }
            #pragma unroll
            for (int j = 0; j < 8; ++j) {
                float acc = 0.f;
                #pragma unroll
                for (int d4 = 0; d4 < 16; ++d4) {
                    float4 qv = *(const float4*)&sq[jb + j][d4*4];
                    acc += qv.x * kr[d4*4+0];
                    acc += qv.y * kr[d4*4+1];
                    acc += qv.z * kr[d4*4+2];
                    acc += qv.w * kr[d4*4+3];
                }
                sc[j][kk] = acc * 0.125f;
            }
        }
        __syncthreads();
        if (tid < 128) {
            int j = tid >> 4, g = tid & 15;
            float mm = -1e30f;
            for (int x = 0; x < 64; ++x) mm = fmaxf(mm, sc[j][g*64 + x]);
            red[j][g] = mm;
        }
        __syncthreads();
        if (tid < 8) {
            float mm = -1e30f;
            for (int g = 0; g < 16; ++g) mm = fmaxf(mm, red[tid][g]);
            rowm[tid] = mm;
        }
        __syncthreads();
        if (tid < 128) {
            int j = tid >> 4, g = tid & 15;
            float m2 = rowm[j], z = 0.f;
            for (int x = 0; x < 64; ++x) {
                float e2 = expf(sc[j][g*64 + x] - m2);
                sc[j][g*64 + x] = e2;
                z += e2;
            }
            red[j][g] = z;
        }
        __syncthreads();
        if (tid < 8) {
            float z = 0.f;
            for (int g = 0; g < 16; ++g) z += red[tid][g];
            rowz[tid] = z;
        }
        __syncthreads();
        if (tid < 64) {
            float acc = pooled[tid];
            for (int j = 0; j < 8; ++j) {
                float ss = 0.f;
                for (int tt = 0; tt < 16; ++tt) ss += sc[j][tid*16 + tt];
                acc += ss / rowz[j];
            }
            pooled[tid] = acc;
        }
        __syncthreads();
    }

    if (tid < 64) {
        float pi = pooled[tid];
        float tot = 0.f, bef = 0.f;
        for (int j2 = 0; j2 < 64; ++j2) {
            float pj = pooled[j2];
            tot += pj;
            if (pj > pi || (pj == pi && j2 < tid)) bef += pj;
        }
        bool att = (bef / tot) < 0.5f;
        unsigned long long bits = __ballot(att);
        if (tid == 0) maskbits[(h << 6) + qb] = bits;
    }
}

// ---------------------------------------------------------------------------
// Kernel B: block-sparse flash attention via bf16 hi/lo split MFMA.
//   S  = Qhi*Khi + Qhi*Klo + Qlo*Khi   (f32-equivalent precision)
//   PV = P*Vhi + P*Vlo                 (V in split precision, P single bf16)
// One block per (h,qb), 4 waves; wave w owns q rows [16w,16w+16).
// MFMA 16x16x32 bf16 layouts (guide-verified):
//   A[m][k]: m=lane&15, k=(lane>>4)*8+j   (8 contiguous bf16 per lane)
//   B from row-major [n][k] storage: n=lane&15, k=(lane>>4)*8+j
//   C/D:     col=lane&15, row=(lane>>4)*4+reg
// K stays row-major [key][d]; V staged transposed [d][key]; P via LDS
// round-trip (C-layout -> A-layout). Q frags hoisted to registers once.
// LDS: 5 x 64x72 bf16 = 46 KB -> 3 blocks/CU.
// ---------------------------------------------------------------------------
__global__ __launch_bounds__(256, 3) void attn_kernel(
    const float* __restrict__ q,
    const float* __restrict__ k,
    const float* __restrict__ v,
    const unsigned long long* __restrict__ maskbits,
    float* __restrict__ out)
{
    const int h    = blockIdx.x >> 6;
    const int qb   = blockIdx.x & 63;
    const int tid  = threadIdx.x;
    const int wave = tid >> 6;
    const int lane = tid & 63;
    const int l16  = lane & 15;
    const int quad = lane >> 4;

    __shared__ unsigned short ks_hi[64][PADB];
    __shared__ unsigned short ks_lo[64][PADB];
    __shared__ unsigned short vt_hi[64][PADB];
    __shared__ unsigned short vt_lo[64][PADB];
    __shared__ unsigned short ps[4][16][PADB];

    // ---- stage Q (bf16 hi/lo) through the K buffers, hoist frags to regs ----
    const float4* qg = (const float4*)(q + ((size_t)h*L_ + (size_t)qb*64)*D_);
    for (int i4 = tid; i4 < 1024; i4 += 256) {
        float4 t = qg[i4];
        int r = i4 >> 4, c = (i4 & 15) << 2;
        ushort4 hi, lo;
        hi.x = f2bf(t.x); lo.x = f2bf(t.x - bf2f(hi.x));
        hi.y = f2bf(t.y); lo.y = f2bf(t.y - bf2f(hi.y));
        hi.z = f2bf(t.z); lo.z = f2bf(t.z - bf2f(hi.z));
        hi.w = f2bf(t.w); lo.w = f2bf(t.w - bf2f(hi.w));
        *(ushort4*)&ks_hi[r][c] = hi;
        *(ushort4*)&ks_lo[r][c] = lo;
    }
    const unsigned long long bm = maskbits[(h << 6) + qb];
    __syncthreads();

    bf16x8 qhi[2], qlo[2];
    #pragma unroll
    for (int kc = 0; kc < 2; ++kc) {
        qhi[kc] = *(const bf16x8*)&ks_hi[wave*16 + l16][kc*32 + quad*8];
        qlo[kc] = *(const bf16x8*)&ks_lo[wave*16 + l16][kc*32 + quad*8];
    }
    __syncthreads();   // K buffers free for reuse

    float m_i[4], l_i[4];
    f32x4 oacc[4];
    #pragma unroll
    for (int r = 0; r < 4; ++r) { m_i[r] = -1e30f; l_i[r] = 0.f; }
    #pragma unroll
    for (int t = 0; t < 4; ++t) oacc[t] = (f32x4){0.f, 0.f, 0.f, 0.f};

    for (int kb = 0; kb < 64; ++kb) {
        if (!((bm >> kb) & 1ull)) continue;

        // ---- stage K row-major + V transposed, both bf16 hi/lo ----
        const float4* kg = (const float4*)(k + ((size_t)h*L_ + (size_t)kb*64)*D_);
        const float*  vg = v + ((size_t)h*L_ + (size_t)kb*64)*D_;
        for (int i4 = tid; i4 < 1024; i4 += 256) {
            float4 t = kg[i4];
            int r = i4 >> 4, c = (i4 & 15) << 2;
            ushort4 hi, lo;
            hi.x = f2bf(t.x); lo.x = f2bf(t.x - bf2f(hi.x));
            hi.y = f2bf(t.y); lo.y = f2bf(t.y - bf2f(hi.y));
            hi.z = f2bf(t.z); lo.z = f2bf(t.z - bf2f(hi.z));
            hi.w = f2bf(t.w); lo.w = f2bf(t.w - bf2f(hi.w));
            *(ushort4*)&ks_hi[r][c] = hi;
            *(ushort4*)&ks_lo[r][c] = lo;
        }
        for (int tsk = tid; tsk < 512; tsk += 256) {
            int rp = tsk >> 4;            // key rows 2rp, 2rp+1
            int c  = (tsk & 15) << 2;     // d columns c..c+3
            float4 a0 = *(const float4*)(vg + (size_t)(2*rp)*D_ + c);
            float4 a1 = *(const float4*)(vg + (size_t)(2*rp+1)*D_ + c);
            #pragma unroll
            for (int j = 0; j < 4; ++j) {
                float x0 = (j==0)?a0.x:(j==1)?a0.y:(j==2)?a0.z:a0.w;
                float x1 = (j==0)?a1.x:(j==1)?a1.y:(j==2)?a1.z:a1.w;
                unsigned short h0 = f2bf(x0), h1 = f2bf(x1);
                *(unsigned*)&vt_hi[c+j][2*rp] = (unsigned)h0 | ((unsigned)h1 << 16);
                unsigned short l0 = f2bf(x0 - bf2f(h0)), l1 = f2bf(x1 - bf2f(h1));
                *(unsigned*)&vt_lo[c+j][2*rp] = (unsigned)l0 | ((unsigned)l1 << 16);
            }
        }
        __syncthreads();

        // ---- S = Q K^T (split precision), 24 MFMAs ----
        f32x4 sacc[4];
        #pragma unroll
        for (int t = 0; t < 4; ++t) sacc[t] = (f32x4){0.f, 0.f, 0.f, 0.f};
        #pragma unroll
        for (int t = 0; t < 4; ++t) {
            #pragma unroll
            for (int kc = 0; kc < 2; ++kc) {
                bf16x8 khi = *(const bf16x8*)&ks_hi[t*16 + l16][kc*32 + quad*8];
                bf16x8 klo = *(const bf16x8*)&ks_lo[t*16 + l16][kc*32 + quad*8];
                sacc[t] = __builtin_amdgcn_mfma_f32_16x16x32_bf16(qhi[kc], khi, sacc[t], 0, 0, 0);
                sacc[t] = __builtin_amdgcn_mfma_f32_16x16x32_bf16(qhi[kc], klo, sacc[t], 0, 0, 0);
                sacc[t] = __builtin_amdgcn_mfma_f32_16x16x32_bf16(qlo[kc], khi, sacc[t], 0, 0, 0);
            }
        }
        #pragma unroll
        for (int t = 0; t < 4; ++t)
            #pragma unroll
            for (int r = 0; r < 4; ++r) sacc[t][r] *= 0.125f;

        // ---- online softmax; rows live in C-layout: row=quad*4+r ----
        float rowmax[4];
        #pragma unroll
        for (int r = 0; r < 4; ++r)
            rowmax[r] = fmaxf(fmaxf(sacc[0][r], sacc[1][r]), fmaxf(sacc[2][r], sacc[3][r]));
        #pragma unroll
        for (int off = 1; off < 16; off <<= 1)
            #pragma unroll
            for (int r = 0; r < 4; ++r)
                rowmax[r] = fmaxf(rowmax[r], __shfl_xor(rowmax[r], off));

        float al[4], rs[4];
        #pragma unroll
        for (int r = 0; r < 4; ++r) {
            float mnew = fmaxf(m_i[r], rowmax[r]);
            al[r] = __expf(m_i[r] - mnew);
            m_i[r] = mnew;
            float acc = 0.f;
            #pragma unroll
            for (int t = 0; t < 4; ++t) {
                float p = __expf(sacc[t][r] - mnew);
                unsigned short pb = f2bf(p);
                ps[wave][quad*4 + r][t*16 + l16] = pb;
                acc += bf2f(pb);   // l from ROUNDED p: normalization self-consistent
            }
            rs[r] = acc;
        }
        #pragma unroll
        for (int off = 1; off < 16; off <<= 1)
            #pragma unroll
            for (int r = 0; r < 4; ++r)
                rs[r] += __shfl_xor(rs[r], off);
        #pragma unroll
        for (int r = 0; r < 4; ++r) l_i[r] = l_i[r] * al[r] + rs[r];
        #pragma unroll
        for (int t = 0; t < 4; ++t)
            #pragma unroll
            for (int r = 0; r < 4; ++r) oacc[t][r] *= al[r];

        // ---- PV: P (A-layout via per-wave LDS region) x V^T, 16 MFMAs ----
        // Same-wave ds_write -> ds_read: ordered by lgkmcnt, no barrier needed.
        bf16x8 pf[2];
        #pragma unroll
        for (int kc = 0; kc < 2; ++kc)
            pf[kc] = *(const bf16x8*)&ps[wave][l16][kc*32 + quad*8];
        #pragma unroll
        for (int t = 0; t < 4; ++t) {
            #pragma unroll
            for (int kc = 0; kc < 2; ++kc) {
                bf16x8 vhif = *(const bf16x8*)&vt_hi[t*16 + l16][kc*32 + quad*8];
                bf16x8 vlof = *(const bf16x8*)&vt_lo[t*16 + l16][kc*32 + quad*8];
                oacc[t] = __builtin_amdgcn_mfma_f32_16x16x32_bf16(pf[kc], vhif, oacc[t], 0, 0, 0);
                oacc[t] = __builtin_amdgcn_mfma_f32_16x16x32_bf16(pf[kc], vlof, oacc[t], 0, 0, 0);
            }
        }
        __syncthreads();   // protect ks/vt before next staging
    }

    // ---- epilogue: O / l, rows = 16*wave + quad*4 + r, cols = 16t + l16 ----
    float* og = out + ((size_t)h*L_ + (size_t)qb*64)*D_ + (size_t)(wave*16 + quad*4)*D_;
    #pragma unroll
    for (int r = 0; r < 4; ++r) {
        float inv = 1.f / l_i[r];
        #pragma unroll
        for (int t = 0; t < 4; ++t)
            og[(size_t)r*D_ + t*16 + l16] = oacc[t][r] * inv;
    }
}

extern "C" void kernel_launch(void* const* d_in, const int* in_sizes, int n_in,
                              void* d_out, int out_size, void* d_ws, size_t ws_size,
                              hipStream_t stream) {
    const float* q = (const float*)d_in[0];
    const float* k = (const float*)d_in[1];
    const float* v = (const float*)d_in[2];
    const int* siq = (const int*)d_in[3];
    const int* sik = (const int*)d_in[4];
    float* out = (float*)d_out;
    unsigned long long* mask = (unsigned long long*)d_ws;  // 512 x 8B = 4 KB

    mask_kernel<<<dim3(H_*NB_), dim3(256), 0, stream>>>(q, k, siq, sik, mask);
    attn_kernel<<<dim3(H_*NB_), dim3(256), 0, stream>>>(q, k, v, mask, out);
}

// Round 4
// 248.520 us; speedup vs baseline: 1.9246x; 1.2183x over previous
//
#include <hip/hip_runtime.h>
#include <hip/hip_bf16.h>

// B=1, H=8, L=4096, D=64; 64x64 blocks; 16 samples/block. Inputs f32, output f32.
#define H_ 8
#define L_ 4096
#define D_ 64
#define NB_ 64

typedef __attribute__((ext_vector_type(8))) short bf16x8;
typedef __attribute__((ext_vector_type(4))) float f32x4;

__device__ __forceinline__ unsigned short f2bf(float x) {   // RNE f32->bf16
    unsigned u = __float_as_uint(x);
    u += 0x7fff + ((u >> 16) & 1);
    return (unsigned short)(u >> 16);
}
__device__ __forceinline__ float bf2f(unsigned short s) {
    return __uint_as_float(((unsigned)s) << 16);
}

// ---------------------------------------------------------------------------
// Kernel A (v2): block mask. One block per (h, slab of 2 q-blocks). Grid 256.
// f32 throughout (decision boundaries!), libm expf, no max-subtraction
// (sampled scores ~N(0,1), |s|<~6 -> exp safe in f32; reorder-noise class).
// 4x4 register tiles over a 32-row x 128-col chunk; E[row][kb] accumulated
// via 16-lane shfl tree + single-writer (no atomics, no races).
// ---------------------------------------------------------------------------
__global__ __launch_bounds__(256) void mask_kernel2(
    const float* __restrict__ q, const float* __restrict__ k,
    const int* __restrict__ sidxq, const int* __restrict__ sidxk,
    unsigned long long* __restrict__ maskbits)
{
    const int h    = blockIdx.x >> 5;
    const int slab = blockIdx.x & 31;   // 2 q-blocks per slab
    const int tid  = threadIdx.x;
    const int rg   = tid >> 5;          // rowgroup 0..7 (rows rg*4..rg*4+3)
    const int cg   = tid & 31;          // colgroup: cols cg, cg+32, cg+64, cg+96

    __shared__ float sq[32][68];        // 32 sampled q rows
    __shared__ float skc[128][68];      // 128-sampled-k-col chunk
    __shared__ float E[32][68];         // exp-mass per (row, kb)  (cols 0..63)
    __shared__ float Z[32];
    __shared__ float pooled[2][66];
    __shared__ int iq[16], ik[16];

    if (tid < 16) { iq[tid] = sidxq[h*16 + tid]; ik[tid] = sidxk[h*16 + tid]; }
    for (int e = tid; e < 32*68; e += 256) (&E[0][0])[e] = 0.f;
    __syncthreads();

    // stage 32 sampled q rows: row j = qbl*16 + t
    for (int i = tid; i < 512; i += 256) {
        int j = i >> 4, d4 = i & 15;
        int grow = h*L_ + (slab*2 + (j >> 4))*64 + iq[j & 15];
        *(float4*)&sq[j][d4*4] = *(const float4*)(q + (size_t)grow*D_ + d4*4);
    }

    for (int cc = 0; cc < 8; ++cc) {
        __syncthreads();   // prev compute done (1st iter: covers sq/E staging)
        // stage chunk: 128 sampled k columns
        for (int i = tid; i < 2048; i += 256) {
            int col = i >> 4, d4 = i & 15;
            int colg = cc*128 + col;
            int grow = h*L_ + (colg >> 4)*64 + ik[colg & 15];
            *(float4*)&skc[col][d4*4] = *(const float4*)(k + (size_t)grow*D_ + d4*4);
        }
        __syncthreads();

        float acc[4][4] = {{0.f,0.f,0.f,0.f},{0.f,0.f,0.f,0.f},
                           {0.f,0.f,0.f,0.f},{0.f,0.f,0.f,0.f}};
        #pragma unroll
        for (int d4 = 0; d4 < 16; ++d4) {
            float4 qv[4];
            #pragma unroll
            for (int i = 0; i < 4; ++i) qv[i] = *(const float4*)&sq[rg*4 + i][d4*4];
            #pragma unroll
            for (int j = 0; j < 4; ++j) {
                float4 kv = *(const float4*)&skc[cg + 32*j][d4*4];
                #pragma unroll
                for (int i = 0; i < 4; ++i)
                    acc[i][j] += qv[i].x*kv.x + qv[i].y*kv.y + qv[i].z*kv.z + qv[i].w*kv.w;
            }
        }
        // exp + accumulate E. For fixed (i,j), the 16 lanes (cg&15) share one
        // (row, kb): colg = cc*128 + cg + 32j -> colg>>4 = cc*8 + (cg>>4) + 2j.
        #pragma unroll
        for (int j = 0; j < 4; ++j) {
            int kb = cc*8 + (cg >> 4) + 2*j;
            #pragma unroll
            for (int i = 0; i < 4; ++i) {
                float p = expf(acc[i][j] * 0.125f);
                p += __shfl_xor(p, 1);
                p += __shfl_xor(p, 2);
                p += __shfl_xor(p, 4);
                p += __shfl_xor(p, 8);
                if ((cg & 15) == 0) E[rg*4 + i][kb] += p;   // unique writer per (row,kb)
            }
        }
    }
    __syncthreads();

    if (tid < 32) {
        float s = 0.f;
        #pragma unroll
        for (int kb = 0; kb < 64; ++kb) s += E[tid][kb];
        Z[tid] = s;
    }
    __syncthreads();
    if (tid < 128) {
        int qbl = tid >> 6, kb = tid & 63;
        float s = 0.f;
        #pragma unroll
        for (int t = 0; t < 16; ++t) {
            int j = qbl*16 + t;
            s += E[j][kb] / Z[j];
        }
        pooled[qbl][kb] = s;
    }
    __syncthreads();
    // top-p 0.5, stable descending rank (ties: lower index first)
    if (tid < 128) {
        int qbl = tid >> 6, kb = tid & 63;
        float pi = pooled[qbl][kb];
        float tot = 0.f, bef = 0.f;
        for (int j2 = 0; j2 < 64; ++j2) {
            float pj = pooled[qbl][j2];
            tot += pj;
            if (pj > pi || (pj == pi && j2 < kb)) bef += pj;
        }
        bool att = (bef / tot) < 0.5f;
        unsigned long long bits = __ballot(att);    // per-wave (qbl 0: wave0, qbl 1: wave1)
        if ((tid & 63) == 0) maskbits[h*64 + slab*2 + qbl] = bits;
    }
}

// ---------------------------------------------------------------------------
// Preprocess: per (h, tile) build bf16 ws tensors ONCE (round-3 did this
// per-(q-block,k-block) -> ~28x redundant VALU + conflicted LDS scatter).
//   Qhi/Qlo: row-major.  Khi: row-major, d-chunks(8 shorts) XOR-swizzled by
//   (row&7).  Vthi/Vtlo: transposed [d][key], key-chunks XOR-swizzled by (d&7).
// Swizzle makes attn fragment reads conflict-free AND staging a linear copy.
// ---------------------------------------------------------------------------
__global__ __launch_bounds__(256) void prep_kernel(
    const float* __restrict__ q, const float* __restrict__ k, const float* __restrict__ v,
    unsigned short* __restrict__ qhi, unsigned short* __restrict__ qlo,
    unsigned short* __restrict__ khi,
    unsigned short* __restrict__ vth, unsigned short* __restrict__ vtl)
{
    const int h  = blockIdx.x >> 6;
    const int tb = blockIdx.x & 63;
    const int tid = threadIdx.x;
    __shared__ float vst[64][68];

    const size_t te = ((size_t)(h*64 + tb)) << 12;   // tile base (elements)
    // --- Q: straight hi/lo ---
    const float4* qg = (const float4*)(q + te);
    for (int i4 = tid; i4 < 1024; i4 += 256) {
        float4 t = qg[i4];
        ushort4 hi, lo;
        hi.x = f2bf(t.x); lo.x = f2bf(t.x - bf2f(hi.x));
        hi.y = f2bf(t.y); lo.y = f2bf(t.y - bf2f(hi.y));
        hi.z = f2bf(t.z); lo.z = f2bf(t.z - bf2f(hi.z));
        hi.w = f2bf(t.w); lo.w = f2bf(t.w - bf2f(hi.w));
        *(ushort4*)(qhi + te + i4*4) = hi;
        *(ushort4*)(qlo + te + i4*4) = lo;
    }
    // --- K: hi only, swizzled ---
    const float4* kg = (const float4*)(k + te);
    for (int i4 = tid; i4 < 1024; i4 += 256) {
        float4 t = kg[i4];
        int r = i4 >> 4, c4 = i4 & 15;
        int sch = (c4 >> 1) ^ (r & 7);
        ushort4 hi;
        hi.x = f2bf(t.x); hi.y = f2bf(t.y); hi.z = f2bf(t.z); hi.w = f2bf(t.w);
        *(ushort4*)(khi + te + r*64 + sch*8 + (c4 & 1)*4) = hi;
    }
    // --- V: transpose via LDS, hi/lo, swizzled ---
    const float4* vg = (const float4*)(v + te);
    for (int i4 = tid; i4 < 1024; i4 += 256) {
        float4 t = vg[i4];
        *(float4*)&vst[i4 >> 4][(i4 & 15)*4] = t;
    }
    __syncthreads();
    for (int u = tid; u < 512; u += 256) {
        int d = u >> 3, kc8 = u & 7;          // keys kc8*8..kc8*8+7
        int sch = kc8 ^ (d & 7);
        ushort4 h0, h1, l0, l1; float x;
        x = vst[kc8*8+0][d]; h0.x = f2bf(x); l0.x = f2bf(x - bf2f(h0.x));
        x = vst[kc8*8+1][d]; h0.y = f2bf(x); l0.y = f2bf(x - bf2f(h0.y));
        x = vst[kc8*8+2][d]; h0.z = f2bf(x); l0.z = f2bf(x - bf2f(h0.z));
        x = vst[kc8*8+3][d]; h0.w = f2bf(x); l0.w = f2bf(x - bf2f(h0.w));
        x = vst[kc8*8+4][d]; h1.x = f2bf(x); l1.x = f2bf(x - bf2f(h1.x));
        x = vst[kc8*8+5][d]; h1.y = f2bf(x); l1.y = f2bf(x - bf2f(h1.y));
        x = vst[kc8*8+6][d]; h1.z = f2bf(x); l1.z = f2bf(x - bf2f(h1.z));
        x = vst[kc8*8+7][d]; h1.w = f2bf(x); l1.w = f2bf(x - bf2f(h1.w));
        *(ushort4*)(vth + te + d*64 + sch*8 + 0) = h0;
        *(ushort4*)(vth + te + d*64 + sch*8 + 4) = h1;
        *(ushort4*)(vtl + te + d*64 + sch*8 + 0) = l0;
        *(ushort4*)(vtl + te + d*64 + sch*8 + 4) = l1;
    }
}

// ---------------------------------------------------------------------------
// Kernel B (fast): block-sparse flash attention from preprocessed ws.
//   S  = (Qhi+Qlo)*Khi   (Q split: dq is row-correlated; K single: dk averages
//                         out under softmax weighting)
//   PV = P*(Vthi+Vtlo)   (V split: its error is direct; P single bf16)
// Register-double-buffered staging: global loads for kb n+1 issued BEFORE the
// barrier, ds_write after compute -> one barrier/iter, load latency overlapped.
// LDS 58 KB -> 2 blocks/CU (grid-limited anyway).
// ---------------------------------------------------------------------------
__global__ __launch_bounds__(256, 2) void attn_fast(
    const unsigned short* __restrict__ qhi, const unsigned short* __restrict__ qlo,
    const unsigned short* __restrict__ khi,
    const unsigned short* __restrict__ vth, const unsigned short* __restrict__ vtl,
    const unsigned long long* __restrict__ maskbits,
    float* __restrict__ out)
{
    const int h    = blockIdx.x >> 6;
    const int qb   = blockIdx.x & 63;
    const int tid  = threadIdx.x;
    const int wave = tid >> 6;
    const int lane = tid & 63;
    const int l16  = lane & 15;
    const int quad = lane >> 4;

    __shared__ __align__(16) unsigned short bufK[2][4096];
    __shared__ __align__(16) unsigned short bufVh[2][4096];
    __shared__ __align__(16) unsigned short bufVl[2][4096];
    __shared__ __align__(16) unsigned short ps[4][16][80];

    // Q fragments straight from global ws (A-layout: m=l16, k=quad*8+j+32kc)
    const size_t qoff = (((size_t)(h*64 + qb)) << 12) + (size_t)(wave*16 + l16)*64;
    bf16x8 qfh[2], qfl[2];
    qfh[0] = *(const bf16x8*)(qhi + qoff + quad*8);
    qfh[1] = *(const bf16x8*)(qhi + qoff + 32 + quad*8);
    qfl[0] = *(const bf16x8*)(qlo + qoff + quad*8);
    qfl[1] = *(const bf16x8*)(qlo + qoff + 32 + quad*8);

    const unsigned long long bm = maskbits[(h << 6) + qb];

    float m_i[4], l_i[4];
    f32x4 oacc[4];
    #pragma unroll
    for (int r = 0; r < 4; ++r) { m_i[r] = -1e30f; l_i[r] = 0.f; }
    #pragma unroll
    for (int t = 0; t < 4; ++t) oacc[t] = (f32x4){0.f, 0.f, 0.f, 0.f};

    bf16x8 rK[2], rVh[2], rVl[2];
    auto stage_load = [&](int kb) {
        const size_t tb = ((size_t)(h*64 + kb)) << 12;
        const bf16x8* gk = (const bf16x8*)(khi + tb);
        const bf16x8* gh = (const bf16x8*)(vth + tb);
        const bf16x8* gl = (const bf16x8*)(vtl + tb);
        rK[0]  = gk[tid]; rK[1]  = gk[tid + 256];
        rVh[0] = gh[tid]; rVh[1] = gh[tid + 256];
        rVl[0] = gl[tid]; rVl[1] = gl[tid + 256];
    };
    auto stage_write = [&](int b) {
        ((bf16x8*)&bufK [b][0])[tid] = rK[0];  ((bf16x8*)&bufK [b][0])[tid+256] = rK[1];
        ((bf16x8*)&bufVh[b][0])[tid] = rVh[0]; ((bf16x8*)&bufVh[b][0])[tid+256] = rVh[1];
        ((bf16x8*)&bufVl[b][0])[tid] = rVl[0]; ((bf16x8*)&bufVl[b][0])[tid+256] = rVl[1];
    };

    auto compute = [&](int b) {
        // S = Q Khi^T
        f32x4 sacc[4];
        #pragma unroll
        for (int t = 0; t < 4; ++t) sacc[t] = (f32x4){0.f, 0.f, 0.f, 0.f};
        #pragma unroll
        for (int t = 0; t < 4; ++t) {
            #pragma unroll
            for (int kc = 0; kc < 2; ++kc) {
                bf16x8 kf = *(const bf16x8*)&bufK[b][(t*16 + l16)*64 + (((kc*4 + quad) ^ (l16 & 7))*8)];
                sacc[t] = __builtin_amdgcn_mfma_f32_16x16x32_bf16(qfh[kc], kf, sacc[t], 0, 0, 0);
                sacc[t] = __builtin_amdgcn_mfma_f32_16x16x32_bf16(qfl[kc], kf, sacc[t], 0, 0, 0);
            }
        }
        #pragma unroll
        for (int t = 0; t < 4; ++t) sacc[t] *= 0.125f;

        // online softmax (rows: quad*4 + r; reductions over 16-lane group)
        float rowmax[4];
        #pragma unroll
        for (int r = 0; r < 4; ++r)
            rowmax[r] = fmaxf(fmaxf(sacc[0][r], sacc[1][r]), fmaxf(sacc[2][r], sacc[3][r]));
        #pragma unroll
        for (int off = 1; off < 16; off <<= 1)
            #pragma unroll
            for (int r = 0; r < 4; ++r)
                rowmax[r] = fmaxf(rowmax[r], __shfl_xor(rowmax[r], off));

        float al[4], rs[4];
        #pragma unroll
        for (int r = 0; r < 4; ++r) {
            float mnew = fmaxf(m_i[r], rowmax[r]);
            al[r] = __expf(m_i[r] - mnew);
            m_i[r] = mnew;
            float acc = 0.f;
            #pragma unroll
            for (int t = 0; t < 4; ++t) {
                float p = __expf(sacc[t][r] - mnew);
                unsigned short pb = f2bf(p);
                ps[wave][quad*4 + r][t*16 + l16] = pb;
                acc += bf2f(pb);    // l from ROUNDED p: self-consistent normalization
            }
            rs[r] = acc;
        }
        #pragma unroll
        for (int off = 1; off < 16; off <<= 1)
            #pragma unroll
            for (int r = 0; r < 4; ++r)
                rs[r] += __shfl_xor(rs[r], off);
        #pragma unroll
        for (int r = 0; r < 4; ++r) l_i[r] = l_i[r] * al[r] + rs[r];
        #pragma unroll
        for (int t = 0; t < 4; ++t)
            #pragma unroll
            for (int r = 0; r < 4; ++r) oacc[t][r] *= al[r];

        // PV (same-wave ps write->read ordered by lgkmcnt)
        bf16x8 pf[2];
        #pragma unroll
        for (int kc = 0; kc < 2; ++kc)
            pf[kc] = *(const bf16x8*)&ps[wave][l16][kc*32 + quad*8];
        #pragma unroll
        for (int t = 0; t < 4; ++t) {
            #pragma unroll
            for (int kc = 0; kc < 2; ++kc) {
                bf16x8 vh = *(const bf16x8*)&bufVh[b][(t*16 + l16)*64 + (((kc*4 + quad) ^ (l16 & 7))*8)];
                bf16x8 vl = *(const bf16x8*)&bufVl[b][(t*16 + l16)*64 + (((kc*4 + quad) ^ (l16 & 7))*8)];
                oacc[t] = __builtin_amdgcn_mfma_f32_16x16x32_bf16(pf[kc], vh, oacc[t], 0, 0, 0);
                oacc[t] = __builtin_amdgcn_mfma_f32_16x16x32_bf16(pf[kc], vl, oacc[t], 0, 0, 0);
            }
        }
    };

    // double-buffered K-loop over attended blocks
    unsigned long long rem = bm;
    int kb0 = (int)__builtin_ctzll(rem); rem &= rem - 1;
    stage_load(kb0);
    stage_write(0);
    int cur = 0;
    for (;;) {
        int nxt = -1;
        if (rem) { nxt = (int)__builtin_ctzll(rem); rem &= rem - 1; stage_load(nxt); }
        __syncthreads();     // buf[cur] writes (prev iter / prologue) visible
        compute(cur);
        if (nxt < 0) break;
        stage_write(cur ^ 1);
        cur ^= 1;
    }

    // epilogue
    float* og = out + ((size_t)h*L_ + (size_t)qb*64)*D_ + (size_t)(wave*16 + quad*4)*D_;
    #pragma unroll
    for (int r = 0; r < 4; ++r) {
        float inv = 1.f / l_i[r];
        #pragma unroll
        for (int t = 0; t < 4; ++t)
            og[(size_t)r*D_ + t*16 + l16] = oacc[t][r] * inv;
    }
}

// ---------------------------------------------------------------------------
// Fallback attention (round-3, proven): used only if ws_size is too small.
// ---------------------------------------------------------------------------
__global__ __launch_bounds__(256, 3) void attn_v3(
    const float* __restrict__ q, const float* __restrict__ k, const float* __restrict__ v,
    const unsigned long long* __restrict__ maskbits, float* __restrict__ out)
{
    const int h = blockIdx.x >> 6, qb = blockIdx.x & 63;
    const int tid = threadIdx.x, wave = tid >> 6, lane = tid & 63;
    const int l16 = lane & 15, quad = lane >> 4;
    __shared__ __align__(16) unsigned short ks_hi[64][72];
    __shared__ __align__(16) unsigned short ks_lo[64][72];
    __shared__ __align__(16) unsigned short vt_hi[64][72];
    __shared__ __align__(16) unsigned short vt_lo[64][72];
    __shared__ __align__(16) unsigned short ps[4][16][72];

    const float4* qg = (const float4*)(q + ((size_t)h*L_ + (size_t)qb*64)*D_);
    for (int i4 = tid; i4 < 1024; i4 += 256) {
        float4 t = qg[i4];
        int r = i4 >> 4, c = (i4 & 15) << 2;
        ushort4 hi, lo;
        hi.x = f2bf(t.x); lo.x = f2bf(t.x - bf2f(hi.x));
        hi.y = f2bf(t.y); lo.y = f2bf(t.y - bf2f(hi.y));
        hi.z = f2bf(t.z); lo.z = f2bf(t.z - bf2f(hi.z));
        hi.w = f2bf(t.w); lo.w = f2bf(t.w - bf2f(hi.w));
        *(ushort4*)&ks_hi[r][c] = hi;
        *(ushort4*)&ks_lo[r][c] = lo;
    }
    const unsigned long long bm = maskbits[(h << 6) + qb];
    __syncthreads();
    bf16x8 qhi[2], qlo[2];
    #pragma unroll
    for (int kc = 0; kc < 2; ++kc) {
        qhi[kc] = *(const bf16x8*)&ks_hi[wave*16 + l16][kc*32 + quad*8];
        qlo[kc] = *(const bf16x8*)&ks_lo[wave*16 + l16][kc*32 + quad*8];
    }
    __syncthreads();
    float m_i[4], l_i[4];
    f32x4 oacc[4];
    #pragma unroll
    for (int r = 0; r < 4; ++r) { m_i[r] = -1e30f; l_i[r] = 0.f; }
    #pragma unroll
    for (int t = 0; t < 4; ++t) oacc[t] = (f32x4){0.f, 0.f, 0.f, 0.f};
    for (int kb = 0; kb < 64; ++kb) {
        if (!((bm >> kb) & 1ull)) continue;
        const float4* kg = (const float4*)(k + ((size_t)h*L_ + (size_t)kb*64)*D_);
        const float*  vg = v + ((size_t)h*L_ + (size_t)kb*64)*D_;
        for (int i4 = tid; i4 < 1024; i4 += 256) {
            float4 t = kg[i4];
            int r = i4 >> 4, c = (i4 & 15) << 2;
            ushort4 hi, lo;
            hi.x = f2bf(t.x); lo.x = f2bf(t.x - bf2f(hi.x));
            hi.y = f2bf(t.y); lo.y = f2bf(t.y - bf2f(hi.y));
            hi.z = f2bf(t.z); lo.z = f2bf(t.z - bf2f(hi.z));
            hi.w = f2bf(t.w); lo.w = f2bf(t.w - bf2f(hi.w));
            *(ushort4*)&ks_hi[r][c] = hi;
            *(ushort4*)&ks_lo[r][c] = lo;
        }
        for (int tsk = tid; tsk < 512; tsk += 256) {
            int rp = tsk >> 4;
            int c  = (tsk & 15) << 2;
            float4 a0 = *(const float4*)(vg + (size_t)(2*rp)*D_ + c);
            float4 a1 = *(const float4*)(vg + (size_t)(2*rp+1)*D_ + c);
            #pragma unroll
            for (int j = 0; j < 4; ++j) {
                float x0 = (j==0)?a0.x:(j==1)?a0.y:(j==2)?a0.z:a0.w;
                float x1 = (j==0)?a1.x:(j==1)?a1.y:(j==2)?a1.z:a1.w;
                unsigned short h0 = f2bf(x0), h1b = f2bf(x1);
                *(unsigned*)&vt_hi[c+j][2*rp] = (unsigned)h0 | ((unsigned)h1b << 16);
                unsigned short lo0 = f2bf(x0 - bf2f(h0)), lo1 = f2bf(x1 - bf2f(h1b));
                *(unsigned*)&vt_lo[c+j][2*rp] = (unsigned)lo0 | ((unsigned)lo1 << 16);
            }
        }
        __syncthreads();
        f32x4 sacc[4];
        #pragma unroll
        for (int t = 0; t < 4; ++t) sacc[t] = (f32x4){0.f, 0.f, 0.f, 0.f};
        #pragma unroll
        for (int t = 0; t < 4; ++t) {
            #pragma unroll
            for (int kc = 0; kc < 2; ++kc) {
                bf16x8 khi2 = *(const bf16x8*)&ks_hi[t*16 + l16][kc*32 + quad*8];
                bf16x8 klo2 = *(const bf16x8*)&ks_lo[t*16 + l16][kc*32 + quad*8];
                sacc[t] = __builtin_amdgcn_mfma_f32_16x16x32_bf16(qhi[kc], khi2, sacc[t], 0, 0, 0);
                sacc[t] = __builtin_amdgcn_mfma_f32_16x16x32_bf16(qhi[kc], klo2, sacc[t], 0, 0, 0);
                sacc[t] = __builtin_amdgcn_mfma_f32_16x16x32_bf16(qlo[kc], khi2, sacc[t], 0, 0, 0);
            }
        }
        #pragma unroll
        for (int t = 0; t < 4; ++t) sacc[t] *= 0.125f;
        float rowmax[4];
        #pragma unroll
        for (int r = 0; r < 4; ++r)
            rowmax[r] = fmaxf(fmaxf(sacc[0][r], sacc[1][r]), fmaxf(sacc[2][r], sacc[3][r]));
        #pragma unroll
        for (int off = 1; off < 16; off <<= 1)
            #pragma unroll
            for (int r = 0; r < 4; ++r)
                rowmax[r] = fmaxf(rowmax[r], __shfl_xor(rowmax[r], off));
        float al[4], rs[4];
        #pragma unroll
        for (int r = 0; r < 4; ++r) {
            float mnew = fmaxf(m_i[r], rowmax[r]);
            al[r] = __expf(m_i[r] - mnew);
            m_i[r] = mnew;
            float acc = 0.f;
            #pragma unroll
            for (int t = 0; t < 4; ++t) {
                float p = __expf(sacc[t][r] - mnew);
                unsigned short pb = f2bf(p);
                ps[wave][quad*4 + r][t*16 + l16] = pb;
                acc += bf2f(pb);
            }
            rs[r] = acc;
        }
        #pragma unroll
        for (int off = 1; off < 16; off <<= 1)
            #pragma unroll
            for (int r = 0; r < 4; ++r)
                rs[r] += __shfl_xor(rs[r], off);
        #pragma unroll
        for (int r = 0; r < 4; ++r) l_i[r] = l_i[r] * al[r] + rs[r];
        #pragma unroll
        for (int t = 0; t < 4; ++t)
            #pragma unroll
            for (int r = 0; r < 4; ++r) oacc[t][r] *= al[r];
        bf16x8 pf[2];
        #pragma unroll
        for (int kc = 0; kc < 2; ++kc)
            pf[kc] = *(const bf16x8*)&ps[wave][l16][kc*32 + quad*8];
        #pragma unroll
        for (int t = 0; t < 4; ++t) {
            #pragma unroll
            for (int kc = 0; kc < 2; ++kc) {
                bf16x8 vhif = *(const bf16x8*)&vt_hi[t*16 + l16][kc*32 + quad*8];
                bf16x8 vlof = *(const bf16x8*)&vt_lo[t*16 + l16][kc*32 + quad*8];
                oacc[t] = __builtin_amdgcn_mfma_f32_16x16x32_bf16(pf[kc], vhif, oacc[t], 0, 0, 0);
                oacc[t] = __builtin_amdgcn_mfma_f32_16x16x32_bf16(pf[kc], vlof, oacc[t], 0, 0, 0);
            }
        }
        __syncthreads();
    }
    float* og = out + ((size_t)h*L_ + (size_t)qb*64)*D_ + (size_t)(wave*16 + quad*4)*D_;
    #pragma unroll
    for (int r = 0; r < 4; ++r) {
        float inv = 1.f / l_i[r];
        #pragma unroll
        for (int t = 0; t < 4; ++t)
            og[(size_t)r*D_ + t*16 + l16] = oacc[t][r] * inv;
    }
}

extern "C" void kernel_launch(void* const* d_in, const int* in_sizes, int n_in,
                              void* d_out, int out_size, void* d_ws, size_t ws_size,
                              hipStream_t stream) {
    const float* q = (const float*)d_in[0];
    const float* k = (const float*)d_in[1];
    const float* v = (const float*)d_in[2];
    const int* siq = (const int*)d_in[3];
    const int* sik = (const int*)d_in[4];
    float* out = (float*)d_out;

    char* ws = (char*)d_ws;
    unsigned long long* mask = (unsigned long long*)ws;          // 4 KB
    const size_t TEN = (size_t)H_*L_*D_;                         // 2,097,152 elems
    unsigned short* qhi = (unsigned short*)(ws + 4096);
    unsigned short* qlo = qhi + TEN;
    unsigned short* khi = qlo + TEN;
    unsigned short* vth = khi + TEN;
    unsigned short* vtl = vth + TEN;
    const size_t need = 4096 + 5*TEN*sizeof(unsigned short);     // ~20 MB

    mask_kernel2<<<dim3(256), dim3(256), 0, stream>>>(q, k, siq, sik, mask);
    if (ws_size >= need) {
        prep_kernel<<<dim3(H_*NB_), dim3(256), 0, stream>>>(q, k, v, qhi, qlo, khi, vth, vtl);
        attn_fast<<<dim3(H_*NB_), dim3(256), 0, stream>>>(qhi, qlo, khi, vth, vtl, mask, out);
    } else {
        attn_v3<<<dim3(H_*NB_), dim3(256), 0, stream>>>(q, k, v, mask, out);
    }
}